// Round 16
// baseline (136.392 us; speedup 1.0000x reference)
//
#include <hip/hip_runtime.h>

typedef __attribute__((ext_vector_type(8))) short bf16x8;
typedef __attribute__((ext_vector_type(4))) float f32x4;

namespace {

constexpr int B = 32, T = 128, V = 128, F = 64, O = 64;
constexpr int TPB = 16;   // 16 t's = 8 pairs per block; grid = (8, 32) = 256 blocks = 1/CU

constexpr size_t WS_THT_OFF = (size_t)B * 64 * 64 * 8 * 2;   // 2 MiB
constexpr size_t WS_LDG_OFF = WS_THT_OFF + 1536 * 8 * 2;     // +24 KiB

__device__ inline unsigned short f2bf(float f) {
    unsigned u = __builtin_bit_cast(unsigned, f);
    u += 0x7FFFu + ((u >> 16) & 1u);
    return (unsigned short)(u >> 16);
}

// ---------------- prep: fragment-major Acat/ThT, ldiag (unchanged) ----------------
__global__ __launch_bounds__(256) void prep(const float* __restrict__ W,
                                            const float* __restrict__ Theta,
                                            unsigned short* __restrict__ acat_f,
                                            unsigned short* __restrict__ tht_f,
                                            float* __restrict__ ldg) {
    const int tid = threadIdx.x;
    if (blockIdx.x == B) {
        for (int i = 0; i < 6; ++i) {
            int fi = tid + i * 256;                 // [0,1536)
            int ks = fi / 768, rem = fi % 768;
            int nf = rem >> 6, lane = rem & 63;
            int n = nf * 16 + (lane & 15);
            int f0 = ks * 32 + (lane >> 4) * 8;
            unsigned short vals[8];
#pragma unroll
            for (int j = 0; j < 8; ++j) {
                int f = f0 + j;
                float v;
                if (n < 64)       v = Theta[f * 64 + n] - Theta[2 * 4096 + f * 64 + n];
                else if (n < 128) v = Theta[4096 + f * 64 + (n - 64)];
                else              v = Theta[2 * 4096 + f * 64 + (n - 128)];
                vals[j] = f2bf(v);
            }
            *(bf16x8*)(tht_f + (size_t)fi * 8) = *(bf16x8*)vals;
        }
        return;
    }
    const int b = blockIdx.x;
    const float* Wb = W + (size_t)b * V * V;
    __shared__ float Wl[V][V + 1];
    for (int i = 0; i < V * V / 256; ++i) {
        int idx = tid + i * 256;
        Wl[idx >> 7][idx & 127] = Wb[idx];
    }
    __syncthreads();
    if (tid < V) {
        float s = 0.f;
        for (int i = 0; i < V; ++i) s += Wl[i][tid];       // deg[u] = sum_i W[i][u]
        ldg[b * V + tid] = s - 1.0f - Wl[tid][tid];        // ldiag
    }
    unsigned short* ab_f = acat_f + (size_t)b * 32768;
    for (int i = 0; i < 16; ++i) {
        int fi = tid + i * 256;                    // [0,4096)
        int ks = fi >> 9, rem = fi & 511;
        int r2 = rem >> 6, lane = rem & 63;
        int u = r2 * 16 + (lane & 15);
        int kv0 = ks * 32 + (lane >> 4) * 8;
        unsigned short vals[8];
#pragma unroll
        for (int j = 0; j < 8; ++j) {
            int kv = kv0 + j, v = kv & 127;
            float wv = Wl[v][u];
            float val = (v == u) ? 0.f : ((kv < 128) ? -wv : 2.f * wv * wv);
            vals[j] = f2bf(val);
        }
        *(bf16x8*)(ab_f + (size_t)fi * 8) = *(bf16x8*)vals;
    }
}

// ---------------- main: t-PAIR superiters; shared operand reads; af from L2 ----------------
__global__ __launch_bounds__(512, 1) void graph_conv_main(
    const float* __restrict__ x, const unsigned short* __restrict__ acat_f,
    const unsigned short* __restrict__ tht_f, const float* __restrict__ ldg,
    float* __restrict__ out) {
    const int t0 = blockIdx.x * TPB, b = blockIdx.y;
    const int tid = threadIdx.x;                 // 0..511
    const int lane = tid & 63, w = tid >> 6;
    const int uq = w & 3;                        // u/v-slab [32uq, 32uq+32)
    const int oh = w >> 2;                       // o-half  [32oh, 32oh+32)
    const int lr = lane & 15, lg = lane >> 4;

    __shared__ __align__(16) unsigned short tht_s[12288];      // 24 KB
    __shared__ __align__(16) unsigned short xbuf[2][2][8192];  // 64 KB: [pairbuf][tp][tile]
    __shared__ __align__(16) unsigned short zc[2][16384];      // 64 KB: [tp][zc1|zc2]; doubles as out-stage
    // total 152 KB -> 1 block/CU

    const float* xb = x + ((size_t)(b * T + t0)) * (V * F);
    const unsigned short* ag = acat_f + (size_t)b * 32768;

    // ---- ldiag fragments ----
    f32x4 ldv[2], ld2v[2];
#pragma unroll
    for (int uf = 0; uf < 2; ++uf) {
        ldv[uf] = *(const f32x4*)(ldg + b * V + 32 * uq + 16 * uf + lg * 4);
        ld2v[uf] = 2.0f * ldv[uf] * ldv[uf];
    }

    // ---- stage tht_s once ----
#pragma unroll
    for (int i = 0; i < 3; ++i) {
        int c = tid + i * 512;
        __builtin_amdgcn_global_load_lds(
            (const __attribute__((address_space(1))) void*)(tht_f + c * 8),
            (__attribute__((address_space(3))) void*)(tht_s + c * 8), 16, 0, 0);
    }

    // pf: one PAIR of x tiles per thread = 8 float4 (pf[0..3]=t even, pf[4..7]=t odd)
    float4 pf[8];
    auto load_pf = [&](int pr) {
        const float4* s0 = (const float4*)(xb + (size_t)(2 * pr) * (V * F));
        const float4* s1 = (const float4*)(xb + (size_t)(2 * pr + 1) * (V * F));
#pragma unroll
        for (int i = 0; i < 4; ++i) pf[i] = s0[tid + i * 512];
#pragma unroll
        for (int i = 0; i < 4; ++i) pf[4 + i] = s1[tid + i * 512];
    };
    auto store_pf = [&](int buf) {
#pragma unroll
        for (int i = 0; i < 8; ++i) {
            int tp = i >> 2;
            int p = tid + (i & 3) * 512;
            int row = p >> 4, c4 = p & 15;
            uint2 q;
            q.x = f2bf(pf[i].x) | ((unsigned)f2bf(pf[i].y) << 16);
            q.y = f2bf(pf[i].z) | ((unsigned)f2bf(pf[i].w) << 16);
            *(uint2*)((char*)xbuf[buf][tp] +
                      row * 128 + (((c4 >> 1) ^ (row & 7)) << 4) + (c4 & 1) * 8) = q;
        }
    };

    // ---- prologue ----
    load_pf(0);
    asm volatile("s_waitcnt vmcnt(0)" ::: "memory");   // tht gl_lds + pf pair0
    __builtin_amdgcn_sched_barrier(0);
    store_pf(0);
    asm volatile("s_waitcnt lgkmcnt(0)" ::: "memory");
    __builtin_amdgcn_sched_barrier(0);
    __builtin_amdgcn_s_barrier();
    __builtin_amdgcn_sched_barrier(0);

    for (int si = 0; si < TPB / 2; ++si) {
        const int cur = si & 1;
        if (si + 1 < TPB / 2) load_pf(si + 1);   // in flight across the whole superiter

        // ---- xa fragments for both t's (8 ds_read_b128) ----
        bf16x8 xa[2][2][2];                      // [tp][rv][kf]
#pragma unroll
        for (int tp = 0; tp < 2; ++tp)
#pragma unroll
            for (int rv = 0; rv < 2; ++rv) {
                const int row = 32 * uq + 16 * rv + lr;
                const char* rp = (const char*)xbuf[cur][tp] + row * 128;
                const int rs = row & 7;
#pragma unroll
                for (int kf = 0; kf < 2; ++kf)
                    xa[tp][rv][kf] = *(const bf16x8*)(rp + (((kf * 4 + lg) ^ rs) << 4));
            }

        // ---- GEMM1 x2t: 12 shared tht reads feed 48 MFMAs ----
        f32x4 acc[2][2][2], z1[2][2][2], z2[2][2][2];   // [tp][uf/rv][of]
#pragma unroll
        for (int tp = 0; tp < 2; ++tp)
#pragma unroll
            for (int a = 0; a < 2; ++a)
#pragma unroll
                for (int o = 0; o < 2; ++o) {
                    acc[tp][a][o] = (f32x4){0.f, 0.f, 0.f, 0.f};
                    z1[tp][a][o] = (f32x4){0.f, 0.f, 0.f, 0.f};
                    z2[tp][a][o] = (f32x4){0.f, 0.f, 0.f, 0.f};
                }
#pragma unroll
        for (int kf = 0; kf < 2; ++kf)
#pragma unroll
            for (int i = 0; i < 2; ++i) {
                bf16x8 t0b = *(const bf16x8*)(tht_s + ((kf * 12 + 0 + 2 * oh + i) * 64 + lane) * 8);
                bf16x8 t1b = *(const bf16x8*)(tht_s + ((kf * 12 + 4 + 2 * oh + i) * 64 + lane) * 8);
                bf16x8 t2b = *(const bf16x8*)(tht_s + ((kf * 12 + 8 + 2 * oh + i) * 64 + lane) * 8);
#pragma unroll
                for (int tp = 0; tp < 2; ++tp)
#pragma unroll
                    for (int rv = 0; rv < 2; ++rv) {
                        acc[tp][rv][i] = __builtin_amdgcn_mfma_f32_16x16x32_bf16(xa[tp][rv][kf], t0b, acc[tp][rv][i], 0, 0, 0);
                        z1[tp][rv][i]  = __builtin_amdgcn_mfma_f32_16x16x32_bf16(xa[tp][rv][kf], t1b, z1[tp][rv][i], 0, 0, 0);
                        z2[tp][rv][i]  = __builtin_amdgcn_mfma_f32_16x16x32_bf16(xa[tp][rv][kf], t2b, z2[tp][rv][i], 0, 0, 0);
                    }
            }

        // ---- diag + zc writes x2t ([o=64][v=128], slot^=lr) ----
#pragma unroll
        for (int tp = 0; tp < 2; ++tp) {
            char* zc1p = (char*)zc[tp];
            char* zc2p = (char*)zc[tp] + 16384;
#pragma unroll
            for (int uf = 0; uf < 2; ++uf)
#pragma unroll
                for (int of = 0; of < 2; ++of) {
                    acc[tp][uf][of] += ldv[uf] * z1[tp][uf][of] + ld2v[uf] * z2[tp][uf][of];
                    const int ro = 32 * oh + of * 16 + lr;
                    const int slot = 4 * uq + 2 * uf + (lg >> 1);
                    const int byte = ro * 256 + (((slot ^ lr)) << 4) + (lg & 1) * 8;
                    f32x4 v1 = z1[tp][uf][of], v2 = z2[tp][uf][of];
                    uint2 q1, q2;
                    q1.x = f2bf(v1[0]) | ((unsigned)f2bf(v1[1]) << 16);
                    q1.y = f2bf(v1[2]) | ((unsigned)f2bf(v1[3]) << 16);
                    q2.x = f2bf(v2[0]) | ((unsigned)f2bf(v2[1]) << 16);
                    q2.y = f2bf(v2[2]) | ((unsigned)f2bf(v2[3]) << 16);
                    *(uint2*)(zc1p + byte) = q1;
                    *(uint2*)(zc2p + byte) = q2;
                }
        }

        asm volatile("s_waitcnt lgkmcnt(0)" ::: "memory");
        __builtin_amdgcn_sched_barrier(0);
        __builtin_amdgcn_s_barrier();                 // barB: zc x2t ready
        __builtin_amdgcn_sched_barrier(0);

        // ---- GEMM2 x2t: 16 shared af reads (global, L2-hot) feed 64 MFMAs; 8 indep 8-deep chains ----
#pragma unroll
        for (int kk = 0; kk < 8; ++kk) {
            bf16x8 af[2];
#pragma unroll
            for (int uf = 0; uf < 2; ++uf)
                af[uf] = *(const bf16x8*)(ag + ((kk * 8 + 2 * uq + uf) * 64 + lane) * 8);
#pragma unroll
            for (int tp = 0; tp < 2; ++tp) {
                const char* zsrc = (char*)zc[tp] + (kk < 4 ? 0 : 16384);
                bf16x8 zb[2];
#pragma unroll
                for (int of = 0; of < 2; ++of) {
                    const int ro = 32 * oh + of * 16 + lr;
                    const int slot = (kk & 3) * 4 + lg;
                    zb[of] = *(const bf16x8*)(zsrc + ro * 256 + ((slot ^ lr) << 4));
                }
#pragma unroll
                for (int uf = 0; uf < 2; ++uf)
#pragma unroll
                    for (int of = 0; of < 2; ++of)
                        acc[tp][uf][of] = __builtin_amdgcn_mfma_f32_16x16x32_bf16(af[uf], zb[of], acc[tp][uf][of], 0, 0, 0);
            }
        }

        // ---- consume pf -> xbuf[cur^1] (compiler inserts the right vmcnt wait) ----
        if (si + 1 < TPB / 2) store_pf(cur ^ 1);

        // ---- barD: all GEMM2 zc reads done before out-stage overwrite ----
        asm volatile("s_waitcnt lgkmcnt(0)" ::: "memory");
        __builtin_amdgcn_sched_barrier(0);
        __builtin_amdgcn_s_barrier();
        __builtin_amdgcn_sched_barrier(0);

        // ---- epilogue A: relu'd acc -> LDS out-stage (zc region, fp32, x2t) ----
#pragma unroll
        for (int tp = 0; tp < 2; ++tp) {
            float* os = (float*)&zc[0][0] + tp * 8192;
#pragma unroll
            for (int uf = 0; uf < 2; ++uf)
#pragma unroll
                for (int of = 0; of < 2; ++of)
#pragma unroll
                    for (int j = 0; j < 4; ++j) {
                        const int u = 32 * uq + 16 * uf + lg * 4 + j;
                        const int o = 32 * oh + 16 * of + lr;
                        const float r = acc[tp][uf][of][j];
                        os[u * 64 + o] = r > 0.f ? r : 0.f;
                    }
        }

        asm volatile("s_waitcnt lgkmcnt(0)" ::: "memory");
        __builtin_amdgcn_sched_barrier(0);
        __builtin_amdgcn_s_barrier();                 // barC: out-stage ready
        __builtin_amdgcn_sched_barrier(0);

        // ---- epilogue B: coalesced dwordx4 stores x2t ----
#pragma unroll
        for (int tp = 0; tp < 2; ++tp) {
            float* obt = out + ((size_t)(b * T + t0 + 2 * si + tp)) * (V * O);
            const float4* osv = (const float4*)((float*)&zc[0][0] + tp * 8192);
#pragma unroll
            for (int i = 0; i < 4; ++i) {
                const int idx = tid + i * 512;
                *(float4*)(obt + idx * 4) = osv[idx];
            }
        }

        // ---- barA: out-stage reads done -> zc free; xbuf[cur^1] complete ----
        asm volatile("s_waitcnt lgkmcnt(0)" ::: "memory");
        __builtin_amdgcn_sched_barrier(0);
        __builtin_amdgcn_s_barrier();
        __builtin_amdgcn_sched_barrier(0);
    }
}

}  // namespace

extern "C" void kernel_launch(void* const* d_in, const int* in_sizes, int n_in,
                              void* d_out, int out_size, void* d_ws, size_t ws_size,
                              hipStream_t stream) {
    const float* x = (const float*)d_in[0];      // (B,T,V,F)
    const float* W = (const float*)d_in[1];      // (B,V,V)
    const float* Theta = (const float*)d_in[2];  // (3,F,O)
    float* outp = (float*)d_out;                 // (B,T,V,O)

    unsigned short* acat_f = (unsigned short*)d_ws;
    unsigned short* tht_f = (unsigned short*)((char*)d_ws + WS_THT_OFF);
    float* ldg = (float*)((char*)d_ws + WS_LDG_OFF);

    prep<<<B + 1, 256, 0, stream>>>(W, Theta, acat_f, tht_f, ldg);
    graph_conv_main<<<dim3(T / TPB, B), 512, 0, stream>>>(x, acat_f, tht_f, ldg, outp);
}